// Round 1
// baseline (244.552 us; speedup 1.0000x reference)
//
#include <hip/hip_runtime.h>
#include <hip/hip_bf16.h>
#include <cmath>

// Problem constants (LocalAttention: B=2, S=2048, D=1024, H=16, HD=64, W=16)
#define S_LEN 2048
#define DMODEL 1024
#define NH 16
#define HD_DIM 64

typedef __bf16 bf16;
typedef __bf16 bf16x8 __attribute__((ext_vector_type(8)));
typedef float f32x4 __attribute__((ext_vector_type(4)));

// ---------------------------------------------------------------------------
// fp32 -> bf16 convert (vectorized, 4 elems/thread)
// ---------------------------------------------------------------------------
__global__ void cvt_f32_bf16(const float* __restrict__ in, bf16* __restrict__ out, int n) {
    int i = (blockIdx.x * blockDim.x + threadIdx.x) * 4;
    if (i < n) {
        float4 v = *(const float4*)(in + i);
        bf16 o[4];
        o[0] = (bf16)v.x; o[1] = (bf16)v.y; o[2] = (bf16)v.z; o[3] = (bf16)v.w;
        *(short4*)(out + i) = *(const short4*)o;
    }
}

// ---------------------------------------------------------------------------
// W [K][N] fp32 -> Wt [N][K] bf16  (LDS-tiled transpose, 64x64 tiles)
// ---------------------------------------------------------------------------
__global__ void transpose_cvt(const float* __restrict__ W, bf16* __restrict__ Wt) {
    __shared__ float tile[64][65];
    int k0 = blockIdx.y * 64, n0 = blockIdx.x * 64;
    int tr = threadIdx.x >> 6, tc = threadIdx.x & 63;
#pragma unroll
    for (int i = 0; i < 16; ++i) {
        int r = tr + i * 4;
        tile[r][tc] = W[(size_t)(k0 + r) * DMODEL + n0 + tc];
    }
    __syncthreads();
#pragma unroll
    for (int i = 0; i < 16; ++i) {
        int r = tr + i * 4;  // local n index
        Wt[(size_t)(n0 + r) * DMODEL + k0 + tc] = (bf16)tile[tc][r];
    }
}

// ---------------------------------------------------------------------------
// concat bq|bk|bv -> bias_all[3072]
// ---------------------------------------------------------------------------
__global__ void bias_concat(const float* __restrict__ bq, const float* __restrict__ bk,
                            const float* __restrict__ bv, float* __restrict__ out) {
    int i = blockIdx.x * 256 + threadIdx.x;  // 0..3071
    float v;
    if (i < 1024)       v = bq[i];
    else if (i < 2048)  v = bk[i - 1024];
    else                v = bv[i - 2048];
    out[i] = v;
}

// ---------------------------------------------------------------------------
// async global->LDS, 16B per lane (dest = wave-uniform base + lane*16)
// ---------------------------------------------------------------------------
__device__ __forceinline__ void gload_lds16(const void* g, void* l) {
    __builtin_amdgcn_global_load_lds((const __attribute__((address_space(1))) void*)g,
                                     (__attribute__((address_space(3))) void*)l, 16, 0, 0);
}

// ---------------------------------------------------------------------------
// GEMM: C[M][N] = A[M][K](bf16) * Bt[N][K](bf16)^T + bias[N]
// m97-style: 128x128 tile, BK=32, 4 waves (2x2 of 64x64), 16x16x32 MFMA
// ---------------------------------------------------------------------------
template <typename OutT>
__global__ __launch_bounds__(256) void gemm_bt(const bf16* __restrict__ A,
                                               const bf16* __restrict__ Bt,
                                               OutT* __restrict__ C,
                                               const float* __restrict__ bias,
                                               int M, int N, int K) {
    __shared__ bf16 As[128 * 32];
    __shared__ bf16 Bs[128 * 32];
    const int tid  = threadIdx.x;
    const int wave = tid >> 6;
    const int lane = tid & 63;
    const int m0 = blockIdx.x * 128;
    const int n0 = blockIdx.y * 128;
    const int wm = (wave >> 1) * 64;   // wave's 64x64 quadrant
    const int wn = (wave & 1) * 64;
    const int lrow = lane & 15;
    const int kh   = lane >> 4;        // 0..3
    const int srow = lane >> 2;        // staging: 16 rows per wave chunk
    const int scol = (lane & 3) * 16;  // byte offset within 64B k-row

    f32x4 acc[4][4] = {};

    for (int k0 = 0; k0 < K; k0 += 32) {
#pragma unroll
        for (int half = 0; half < 2; ++half) {
            int rbase = half * 64 + wave * 16;
            // A tile rows m0+rbase+srow, 64B per row of K-slice
            const char* ga = (const char*)(A + (size_t)(m0 + rbase + srow) * K + k0) + scol;
            gload_lds16(ga, (char*)As + rbase * 64);
            const char* gb = (const char*)(Bt + (size_t)(n0 + rbase + srow) * K + k0) + scol;
            gload_lds16(gb, (char*)Bs + rbase * 64);
        }
        __syncthreads();
        bf16x8 af[4], bfr[4];
#pragma unroll
        for (int mf = 0; mf < 4; ++mf)
            af[mf] = *(const bf16x8*)&As[(wm + mf * 16 + lrow) * 32 + kh * 8];
#pragma unroll
        for (int nf = 0; nf < 4; ++nf)
            bfr[nf] = *(const bf16x8*)&Bs[(wn + nf * 16 + lrow) * 32 + kh * 8];
#pragma unroll
        for (int mf = 0; mf < 4; ++mf)
#pragma unroll
            for (int nf = 0; nf < 4; ++nf)
                acc[mf][nf] = __builtin_amdgcn_mfma_f32_16x16x32_bf16(af[mf], bfr[nf], acc[mf][nf], 0, 0, 0);
        __syncthreads();
    }

    // epilogue: D row = (lane>>4)*4 + r, col = lane&15
#pragma unroll
    for (int mf = 0; mf < 4; ++mf) {
#pragma unroll
        for (int nf = 0; nf < 4; ++nf) {
            int col = n0 + wn + nf * 16 + lrow;
            float bv_ = bias[col];
#pragma unroll
            for (int r = 0; r < 4; ++r) {
                int row = m0 + wm + mf * 16 + kh * 4 + r;
                C[(size_t)row * N + col] = (OutT)(acc[mf][nf][r] + bv_);
            }
        }
    }
}

// ---------------------------------------------------------------------------
// V column sums per (b,h): vsum[b*16+h][d] = sum_j v[b,j,h*64+d]
// ---------------------------------------------------------------------------
__global__ void vsum_k(const bf16* __restrict__ qkv, float* __restrict__ vsum) {
    int bh = blockIdx.x;  // 0..31
    int b = bh >> 4, h = bh & 15;
    int d = threadIdx.x & 63, part = threadIdx.x >> 6;
    __shared__ float p[4][64];
    float acc = 0.f;
    for (int j = part; j < S_LEN; j += 4)
        acc += (float)qkv[(size_t)(b * S_LEN + j) * 3072 + 2048 + h * 64 + d];
    p[part][d] = acc;
    __syncthreads();
    if (threadIdx.x < 64)
        vsum[bh * 64 + threadIdx.x] =
            p[0][threadIdx.x] + p[1][threadIdx.x] + p[2][threadIdx.x] + p[3][threadIdx.x];
}

// ---------------------------------------------------------------------------
// Band attention. Per block: one (b, h, 64-row i-tile).
//   w_ij = expm1(q_i . k_j / 8)  for |i-j| <= 8, 0 <= j < S
//   ctx_i = (sum_j w_ij v_j + Vsum) / (sum_j w_ij + S)
// ---------------------------------------------------------------------------
__global__ __launch_bounds__(256) void band_attn(const bf16* __restrict__ qkv,
                                                 const float* __restrict__ vsum,
                                                 bf16* __restrict__ ctx) {
    int bid = blockIdx.x;
    int it = bid & 31;
    int h  = (bid >> 5) & 15;
    int b  = bid >> 9;
    const int i0 = it * 64;

    __shared__ bf16 qs[64 * 72];
    __shared__ bf16 ks[80 * 72];
    __shared__ bf16 vs[80 * 72];
    __shared__ float wsc[64 * 19];
    __shared__ float wsum[64];

    int tid = threadIdx.x;

    // load q tile (64 rows x 128B)
    for (int idx = tid; idx < 64 * 8; idx += 256) {
        int r = idx >> 3, c = idx & 7;
        size_t g = (size_t)(b * S_LEN + i0 + r) * 3072 + h * 64 + c * 8;
        *(int4*)&qs[r * 72 + c * 8] = *(const int4*)&qkv[g];
    }
    // load k/v tiles (80 rows, j = i0-8+r), zero-fill out of range
    for (int idx = tid; idx < 80 * 8; idx += 256) {
        int r = idx >> 3, c = idx & 7;
        int j = i0 - 8 + r;
        int4 kv = {0, 0, 0, 0}, vv = {0, 0, 0, 0};
        if (j >= 0 && j < S_LEN) {
            size_t base = (size_t)(b * S_LEN + j) * 3072 + h * 64 + c * 8;
            kv = *(const int4*)&qkv[base + 1024];
            vv = *(const int4*)&qkv[base + 2048];
        }
        *(int4*)&ks[r * 72 + c * 8] = kv;
        *(int4*)&vs[r * 72 + c * 8] = vv;
    }
    __syncthreads();

    // phase 2: band weights
    {
        int i = tid >> 2, jg = tid & 3;
        for (int jj = jg; jj < 17; jj += 4) {
            int j = i0 + i - 8 + jj;
            float w = 0.f;
            if (j >= 0 && j < S_LEN) {
                float dot = 0.f;
#pragma unroll
                for (int c = 0; c < 8; ++c) {
                    bf16x8 qv = *(const bf16x8*)&qs[i * 72 + c * 8];
                    bf16x8 kv = *(const bf16x8*)&ks[(i + jj) * 72 + c * 8];
#pragma unroll
                    for (int e = 0; e < 8; ++e) dot += (float)qv[e] * (float)kv[e];
                }
                w = expm1f(dot * 0.125f);
            }
            wsc[i * 19 + jj] = w;
        }
    }
    __syncthreads();
    if (tid < 64) {
        float s = 0.f;
#pragma unroll
        for (int jj = 0; jj < 17; ++jj) s += wsc[tid * 19 + jj];
        wsum[tid] = s + (float)S_LEN;
    }
    __syncthreads();

    // phase 3: weighted V accumulation
    {
        int d = tid & 63, ig = tid >> 6;
        float vbase = vsum[(b * NH + h) * HD_DIM + d];
        for (int i = ig; i < 64; i += 4) {
            float acc = vbase;
#pragma unroll
            for (int jj = 0; jj < 17; ++jj)
                acc += wsc[i * 19 + jj] * (float)vs[(i + jj) * 72 + d];
            ctx[(size_t)(b * S_LEN + i0 + i) * 1024 + h * 64 + d] = (bf16)(acc / wsum[i]);
        }
    }
}

// ---------------------------------------------------------------------------
extern "C" void kernel_launch(void* const* d_in, const int* in_sizes, int n_in,
                              void* d_out, int out_size, void* d_ws, size_t ws_size,
                              hipStream_t stream) {
    const float* x  = (const float*)d_in[0];
    const float* Wq = (const float*)d_in[1];
    const float* Wk = (const float*)d_in[2];
    const float* Wv = (const float*)d_in[3];
    const float* Wo = (const float*)d_in[4];
    const float* bq = (const float*)d_in[5];
    const float* bk = (const float*)d_in[6];
    const float* bv = (const float*)d_in[7];
    const float* bo = (const float*)d_in[8];

    char* ws = (char*)d_ws;
    bf16*  xb    = (bf16*)(ws);                       // 8 MB   x as bf16
    bf16*  wtall = (bf16*)(ws + 8388608);             // 6 MB   [Wq^T;Wk^T;Wv^T] bf16 [3072][1024]
    bf16*  wot   = (bf16*)(ws + 14680064);            // 2 MB   Wo^T bf16 [1024][1024]
    float* ball  = (float*)(ws + 16777216);           // 12 KB  bias concat [3072]
    bf16*  qkv   = (bf16*)(ws + 16789504);            // 24 MB  [4096][3072] bf16
    bf16*  ctxb  = (bf16*)(ws + 41955328);            // 8 MB   ctx bf16 [4096][1024]
    float* vsm   = (float*)(ws + 50343936);           // 8 KB   [32][64]

    cvt_f32_bf16<<<4096, 256, 0, stream>>>(x, xb, 4194304);
    dim3 tg(16, 16);
    transpose_cvt<<<tg, 256, 0, stream>>>(Wq, wtall);
    transpose_cvt<<<tg, 256, 0, stream>>>(Wk, wtall + 1024 * 1024);
    transpose_cvt<<<tg, 256, 0, stream>>>(Wv, wtall + 2 * 1024 * 1024);
    transpose_cvt<<<tg, 256, 0, stream>>>(Wo, wot);
    bias_concat<<<12, 256, 0, stream>>>(bq, bk, bv, ball);

    // QKV projection: [4096][1024] x [3072][1024]^T -> [4096][3072] bf16
    gemm_bt<bf16><<<dim3(32, 24), 256, 0, stream>>>(xb, wtall, qkv, ball, 4096, 3072, 1024);

    vsum_k<<<32, 256, 0, stream>>>(qkv, vsm);
    band_attn<<<1024, 256, 0, stream>>>(qkv, vsm, ctxb);

    // output projection -> d_out fp32
    gemm_bt<float><<<dim3(32, 8), 256, 0, stream>>>(ctxb, wot, (float*)d_out, bo, 4096, 1024, 1024);
}

// Round 2
// 115.352 us; speedup vs baseline: 2.1201x; 2.1201x over previous
//
#include <hip/hip_runtime.h>
#include <hip/hip_bf16.h>
#include <cmath>

// Problem constants (LocalAttention: B=2, S=2048, D=1024, H=16, HD=64, W=16)
#define S_LEN 2048
#define DMODEL 1024
#define NH 16
#define HD_DIM 64

typedef __bf16 bf16;
typedef __bf16 bf16x8 __attribute__((ext_vector_type(8)));
typedef float f32x4 __attribute__((ext_vector_type(4)));

// ---------------------------------------------------------------------------
// fp32 -> bf16 convert (vectorized, 4 elems/thread)
// ---------------------------------------------------------------------------
__global__ void cvt_f32_bf16(const float* __restrict__ in, bf16* __restrict__ out, int n) {
    int i = (blockIdx.x * blockDim.x + threadIdx.x) * 4;
    if (i < n) {
        float4 v = *(const float4*)(in + i);
        bf16 o[4];
        o[0] = (bf16)v.x; o[1] = (bf16)v.y; o[2] = (bf16)v.z; o[3] = (bf16)v.w;
        *(short4*)(out + i) = *(const short4*)o;
    }
}

// ---------------------------------------------------------------------------
// W [K][N] fp32 -> Wt [N][K] bf16  (LDS-tiled transpose, 64x64 tiles)
// ---------------------------------------------------------------------------
__global__ void transpose_cvt(const float* __restrict__ W, bf16* __restrict__ Wt) {
    __shared__ float tile[64][65];
    int k0 = blockIdx.y * 64, n0 = blockIdx.x * 64;
    int tr = threadIdx.x >> 6, tc = threadIdx.x & 63;
#pragma unroll
    for (int i = 0; i < 16; ++i) {
        int r = tr + i * 4;
        tile[r][tc] = W[(size_t)(k0 + r) * DMODEL + n0 + tc];
    }
    __syncthreads();
#pragma unroll
    for (int i = 0; i < 16; ++i) {
        int r = tr + i * 4;  // local n index
        Wt[(size_t)(n0 + r) * DMODEL + k0 + tc] = (bf16)tile[tc][r];
    }
}

// ---------------------------------------------------------------------------
// concat bq|bk|bv -> bias_all[3072]
// ---------------------------------------------------------------------------
__global__ void bias_concat(const float* __restrict__ bq, const float* __restrict__ bk,
                            const float* __restrict__ bv, float* __restrict__ out) {
    int i = blockIdx.x * 256 + threadIdx.x;  // 0..3071
    float v;
    if (i < 1024)       v = bq[i];
    else if (i < 2048)  v = bk[i - 1024];
    else                v = bv[i - 2048];
    out[i] = v;
}

// ---------------------------------------------------------------------------
// async global->LDS, 16B per lane (dest = wave-uniform base + lane*16)
// ---------------------------------------------------------------------------
__device__ __forceinline__ void gload_lds16(const void* g, void* l) {
    __builtin_amdgcn_global_load_lds((const __attribute__((address_space(1))) void*)g,
                                     (__attribute__((address_space(3))) void*)l, 16, 0, 0);
}

// ---------------------------------------------------------------------------
// GEMM: C[M][N] = A[M][K](bf16) * Bt[N][K](bf16)^T + bias[N]
// m97-style: 128x128 tile, BK=32, 4 waves (2x2 of 64x64), 16x16x32 MFMA
// ---------------------------------------------------------------------------
template <typename OutT>
__global__ __launch_bounds__(256) void gemm_bt(const bf16* __restrict__ A,
                                               const bf16* __restrict__ Bt,
                                               OutT* __restrict__ C,
                                               const float* __restrict__ bias,
                                               int M, int N, int K) {
    __shared__ bf16 As[128 * 32];
    __shared__ bf16 Bs[128 * 32];
    const int tid  = threadIdx.x;
    const int wave = tid >> 6;
    const int lane = tid & 63;
    const int m0 = blockIdx.x * 128;
    const int n0 = blockIdx.y * 128;
    const int wm = (wave >> 1) * 64;   // wave's 64x64 quadrant
    const int wn = (wave & 1) * 64;
    const int lrow = lane & 15;
    const int kh   = lane >> 4;        // 0..3
    const int srow = lane >> 2;        // staging: 16 rows per wave chunk
    const int scol = (lane & 3) * 16;  // byte offset within 64B k-row

    f32x4 acc[4][4] = {};

    for (int k0 = 0; k0 < K; k0 += 32) {
#pragma unroll
        for (int half = 0; half < 2; ++half) {
            int rbase = half * 64 + wave * 16;
            // A tile rows m0+rbase+srow, 64B per row of K-slice
            const char* ga = (const char*)(A + (size_t)(m0 + rbase + srow) * K + k0) + scol;
            gload_lds16(ga, (char*)As + rbase * 64);
            const char* gb = (const char*)(Bt + (size_t)(n0 + rbase + srow) * K + k0) + scol;
            gload_lds16(gb, (char*)Bs + rbase * 64);
        }
        __syncthreads();
        bf16x8 af[4], bfr[4];
#pragma unroll
        for (int mf = 0; mf < 4; ++mf)
            af[mf] = *(const bf16x8*)&As[(wm + mf * 16 + lrow) * 32 + kh * 8];
#pragma unroll
        for (int nf = 0; nf < 4; ++nf)
            bfr[nf] = *(const bf16x8*)&Bs[(wn + nf * 16 + lrow) * 32 + kh * 8];
#pragma unroll
        for (int mf = 0; mf < 4; ++mf)
#pragma unroll
            for (int nf = 0; nf < 4; ++nf)
                acc[mf][nf] = __builtin_amdgcn_mfma_f32_16x16x32_bf16(af[mf], bfr[nf], acc[mf][nf], 0, 0, 0);
        __syncthreads();
    }

    // epilogue: D row = (lane>>4)*4 + r, col = lane&15
#pragma unroll
    for (int mf = 0; mf < 4; ++mf) {
#pragma unroll
        for (int nf = 0; nf < 4; ++nf) {
            int col = n0 + wn + nf * 16 + lrow;
            float bv_ = bias[col];
#pragma unroll
            for (int r = 0; r < 4; ++r) {
                int row = m0 + wm + mf * 16 + kh * 4 + r;
                C[(size_t)row * N + col] = (OutT)(acc[mf][nf][r] + bv_);
            }
        }
    }
}

// ---------------------------------------------------------------------------
// V column sums, stage 1: partial[b*64+chunk][1024] = sum of 32 rows of V
// grid = 128 blocks (b*64+chunk), 256 threads.
// Each thread: column-group cg (8 cols), j-part jp (16 rows each).
// ---------------------------------------------------------------------------
__global__ __launch_bounds__(256) void vsum_part(const bf16* __restrict__ qkv,
                                                 float* __restrict__ part) {
    int blk = blockIdx.x;       // 0..127
    int b = blk >> 6, chunk = blk & 63;
    int cg = threadIdx.x & 127; // column group of 8
    int jp = threadIdx.x >> 7;  // 0..1
    int j0 = chunk * 32 + jp * 16;

    float acc[8] = {};
#pragma unroll
    for (int r = 0; r < 16; ++r) {
        int j = j0 + r;
        bf16x8 v = *(const bf16x8*)&qkv[(size_t)(b * S_LEN + j) * 3072 + 2048 + cg * 8];
#pragma unroll
        for (int e = 0; e < 8; ++e) acc[e] += (float)v[e];
    }

    __shared__ float red[256][8];
#pragma unroll
    for (int e = 0; e < 8; ++e) red[threadIdx.x][e] = acc[e];
    __syncthreads();
    if (jp == 0) {
        float* outp = part + ((size_t)blk << 10) + cg * 8;
#pragma unroll
        for (int e = 0; e < 8; ++e)
            outp[e] = red[threadIdx.x][e] + red[threadIdx.x + 128][e];
    }
}

// ---------------------------------------------------------------------------
// V column sums, stage 2: vsum[b*1024 + col] = sum over 64 chunks
// grid = 8 blocks x 256 threads (one thread per (b,col))
// ---------------------------------------------------------------------------
__global__ void vsum_final(const float* __restrict__ part, float* __restrict__ vsum) {
    int idx = blockIdx.x * 256 + threadIdx.x;  // 0..2047
    int b = idx >> 10, col = idx & 1023;
    float s = 0.f;
#pragma unroll
    for (int c = 0; c < 64; ++c) s += part[(((size_t)b * 64 + c) << 10) + col];
    vsum[idx] = s;  // layout [b][h][d] == b*1024 + h*64 + d
}

// ---------------------------------------------------------------------------
// Band attention. Per block: one (b, h, 64-row i-tile).
//   w_ij = expm1(q_i . k_j / 8)  for |i-j| <= 8, 0 <= j < S
//   ctx_i = (sum_j w_ij v_j + Vsum) / (sum_j w_ij + S)
// ---------------------------------------------------------------------------
__global__ __launch_bounds__(256) void band_attn(const bf16* __restrict__ qkv,
                                                 const float* __restrict__ vsum,
                                                 bf16* __restrict__ ctx) {
    int bid = blockIdx.x;
    int it = bid & 31;
    int h  = (bid >> 5) & 15;
    int b  = bid >> 9;
    const int i0 = it * 64;

    __shared__ bf16 qs[64 * 72];
    __shared__ bf16 ks[80 * 72];
    __shared__ bf16 vs[80 * 72];
    __shared__ float wsc[64 * 19];
    __shared__ float wsum[64];

    int tid = threadIdx.x;

    // load q tile (64 rows x 128B)
    for (int idx = tid; idx < 64 * 8; idx += 256) {
        int r = idx >> 3, c = idx & 7;
        size_t g = (size_t)(b * S_LEN + i0 + r) * 3072 + h * 64 + c * 8;
        *(int4*)&qs[r * 72 + c * 8] = *(const int4*)&qkv[g];
    }
    // load k/v tiles (80 rows, j = i0-8+r), zero-fill out of range
    for (int idx = tid; idx < 80 * 8; idx += 256) {
        int r = idx >> 3, c = idx & 7;
        int j = i0 - 8 + r;
        int4 kv = {0, 0, 0, 0}, vv = {0, 0, 0, 0};
        if (j >= 0 && j < S_LEN) {
            size_t base = (size_t)(b * S_LEN + j) * 3072 + h * 64 + c * 8;
            kv = *(const int4*)&qkv[base + 1024];
            vv = *(const int4*)&qkv[base + 2048];
        }
        *(int4*)&ks[r * 72 + c * 8] = kv;
        *(int4*)&vs[r * 72 + c * 8] = vv;
    }
    __syncthreads();

    // phase 2: band weights
    {
        int i = tid >> 2, jg = tid & 3;
        for (int jj = jg; jj < 17; jj += 4) {
            int j = i0 + i - 8 + jj;
            float w = 0.f;
            if (j >= 0 && j < S_LEN) {
                float dot = 0.f;
#pragma unroll
                for (int c = 0; c < 8; ++c) {
                    bf16x8 qv = *(const bf16x8*)&qs[i * 72 + c * 8];
                    bf16x8 kv = *(const bf16x8*)&ks[(i + jj) * 72 + c * 8];
#pragma unroll
                    for (int e = 0; e < 8; ++e) dot += (float)qv[e] * (float)kv[e];
                }
                w = expm1f(dot * 0.125f);
            }
            wsc[i * 19 + jj] = w;
        }
    }
    __syncthreads();
    if (tid < 64) {
        float s = 0.f;
#pragma unroll
        for (int jj = 0; jj < 17; ++jj) s += wsc[tid * 19 + jj];
        wsum[tid] = s + (float)S_LEN;
    }
    __syncthreads();

    // phase 3: weighted V accumulation
    {
        int d = tid & 63, ig = tid >> 6;
        float vbase = vsum[(b * NH + h) * HD_DIM + d];
        for (int i = ig; i < 64; i += 4) {
            float acc = vbase;
#pragma unroll
            for (int jj = 0; jj < 17; ++jj)
                acc += wsc[i * 19 + jj] * (float)vs[(i + jj) * 72 + d];
            ctx[(size_t)(b * S_LEN + i0 + i) * 1024 + h * 64 + d] = (bf16)(acc / wsum[i]);
        }
    }
}

// ---------------------------------------------------------------------------
extern "C" void kernel_launch(void* const* d_in, const int* in_sizes, int n_in,
                              void* d_out, int out_size, void* d_ws, size_t ws_size,
                              hipStream_t stream) {
    const float* x  = (const float*)d_in[0];
    const float* Wq = (const float*)d_in[1];
    const float* Wk = (const float*)d_in[2];
    const float* Wv = (const float*)d_in[3];
    const float* Wo = (const float*)d_in[4];
    const float* bq = (const float*)d_in[5];
    const float* bk = (const float*)d_in[6];
    const float* bv = (const float*)d_in[7];
    const float* bo = (const float*)d_in[8];

    char* ws = (char*)d_ws;
    bf16*  xb    = (bf16*)(ws);                       // 8 MB   x as bf16
    bf16*  wtall = (bf16*)(ws + 8388608);             // 6 MB   [Wq^T;Wk^T;Wv^T] bf16 [3072][1024]
    bf16*  wot   = (bf16*)(ws + 14680064);            // 2 MB   Wo^T bf16 [1024][1024]
    float* ball  = (float*)(ws + 16777216);           // 12 KB  bias concat [3072]
    bf16*  qkv   = (bf16*)(ws + 16789504);            // 24 MB  [4096][3072] bf16
    bf16*  ctxb  = (bf16*)(ws + 41955328);            // 8 MB   ctx bf16 [4096][1024]
    float* vsm   = (float*)(ws + 50343936);           // 8 KB   [32][64] == [b][h][d]
    // vsum partials alias the xb region: xb is dead after the QKV GEMM,
    // and vsum_part runs strictly after it on the same stream.
    float* vpart = (float*)(ws);                      // 512 KB [128][1024]

    cvt_f32_bf16<<<4096, 256, 0, stream>>>(x, xb, 4194304);
    dim3 tg(16, 16);
    transpose_cvt<<<tg, 256, 0, stream>>>(Wq, wtall);
    transpose_cvt<<<tg, 256, 0, stream>>>(Wk, wtall + 1024 * 1024);
    transpose_cvt<<<tg, 256, 0, stream>>>(Wv, wtall + 2 * 1024 * 1024);
    transpose_cvt<<<tg, 256, 0, stream>>>(Wo, wot);
    bias_concat<<<12, 256, 0, stream>>>(bq, bk, bv, ball);

    // QKV projection: [4096][1024] x [3072][1024]^T -> [4096][3072] bf16
    gemm_bt<bf16><<<dim3(32, 24), 256, 0, stream>>>(xb, wtall, qkv, ball, 4096, 3072, 1024);

    vsum_part<<<128, 256, 0, stream>>>(qkv, vpart);
    vsum_final<<<8, 256, 0, stream>>>(vpart, vsm);
    band_attn<<<1024, 256, 0, stream>>>(qkv, vsm, ctxb);

    // output projection -> d_out fp32
    gemm_bt<float><<<dim3(32, 8), 256, 0, stream>>>(ctxb, wot, (float*)d_out, bo, 4096, 1024, 1024);
}

// Round 3
// 108.520 us; speedup vs baseline: 2.2535x; 1.0630x over previous
//
#include <hip/hip_runtime.h>
#include <hip/hip_bf16.h>
#include <cmath>

// Problem constants (LocalAttention: B=2, S=2048, D=1024, H=16, HD=64, W=16)
#define S_LEN 2048
#define DMODEL 1024
#define NH 16
#define HD_DIM 64

typedef __bf16 bf16;
typedef __bf16 bf16x8 __attribute__((ext_vector_type(8)));
typedef float f32x4 __attribute__((ext_vector_type(4)));

// ---------------------------------------------------------------------------
// fp32 -> bf16 convert (vectorized, 4 elems/thread)
// ---------------------------------------------------------------------------
__global__ void cvt_f32_bf16(const float* __restrict__ in, bf16* __restrict__ out, int n) {
    int i = (blockIdx.x * blockDim.x + threadIdx.x) * 4;
    if (i < n) {
        float4 v = *(const float4*)(in + i);
        bf16 o[4];
        o[0] = (bf16)v.x; o[1] = (bf16)v.y; o[2] = (bf16)v.z; o[3] = (bf16)v.w;
        *(short4*)(out + i) = *(const short4*)o;
    }
}

// ---------------------------------------------------------------------------
// W [K][N] fp32 -> Wt [N][K] bf16  (LDS-tiled transpose, 64x64 tiles)
// ---------------------------------------------------------------------------
__global__ void transpose_cvt(const float* __restrict__ W, bf16* __restrict__ Wt) {
    __shared__ float tile[64][65];
    int k0 = blockIdx.y * 64, n0 = blockIdx.x * 64;
    int tr = threadIdx.x >> 6, tc = threadIdx.x & 63;
#pragma unroll
    for (int i = 0; i < 16; ++i) {
        int r = tr + i * 4;
        tile[r][tc] = W[(size_t)(k0 + r) * DMODEL + n0 + tc];
    }
    __syncthreads();
#pragma unroll
    for (int i = 0; i < 16; ++i) {
        int r = tr + i * 4;  // local n index
        Wt[(size_t)(n0 + r) * DMODEL + k0 + tc] = (bf16)tile[tc][r];
    }
}

// ---------------------------------------------------------------------------
// concat bq|bk|bv -> bias_all[3072]
// ---------------------------------------------------------------------------
__global__ void bias_concat(const float* __restrict__ bq, const float* __restrict__ bk,
                            const float* __restrict__ bv, float* __restrict__ out) {
    int i = blockIdx.x * 256 + threadIdx.x;  // 0..3071
    float v;
    if (i < 1024)       v = bq[i];
    else if (i < 2048)  v = bk[i - 1024];
    else                v = bv[i - 2048];
    out[i] = v;
}

// ---------------------------------------------------------------------------
// async global->LDS, 16B per lane (dest = wave-uniform base + lane*16)
// ---------------------------------------------------------------------------
__device__ __forceinline__ void gload_lds16(const void* g, void* l) {
    __builtin_amdgcn_global_load_lds((const __attribute__((address_space(1))) void*)g,
                                     (__attribute__((address_space(3))) void*)l, 16, 0, 0);
}

// ===========================================================================
// 256x256 8-phase GEMM (T2 swizzle + T3/T4 counted vmcnt + T5 setprio)
//   C[M][N](bf16) = A[M][K](bf16) * Bt[N][K](bf16)^T + bias[N]
//   512 threads = 8 waves (2 M x 4 N), per-wave 128x64 output.
//   LDS 128 KiB: A[2dbuf][2half][64rows x 64cols... stored 128x64 per half],
//   B same, both XOR-swizzled (byte ^= ((row&7)<<4)) on the read side with
//   inverse-swizzled global staging source (linear gload_lds dest).
//   Requires M%256==0, N%256==0, KDIM%128==0, KDIM>=256.
// ===========================================================================
#define BAR() asm volatile("s_barrier" ::: "memory")
#define VMC(N) asm volatile("s_waitcnt vmcnt(" #N ")" ::: "memory")

#define STAGE_A(T, H, DB) do {                                                         \
    gload_lds16(aSrc + (size_t)((H) * 128) * KDIM + (T) * 64,                          \
                aDst + (DB) * 32768 + (H) * 16384);                                    \
    gload_lds16(aSrc + (size_t)((H) * 128 + 64) * KDIM + (T) * 64,                     \
                aDst + (DB) * 32768 + (H) * 16384 + 8192);                             \
} while (0)
#define STAGE_B(T, H, DB) do {                                                         \
    gload_lds16(bSrc + (size_t)((H) * 128) * KDIM + (T) * 64,                          \
                bDst + (DB) * 32768 + (H) * 16384);                                    \
    gload_lds16(bSrc + (size_t)((H) * 128 + 64) * KDIM + (T) * 64,                     \
                bDst + (DB) * 32768 + (H) * 16384 + 8192);                             \
} while (0)
#define RD_A(D, MH) do {                                                               \
    _Pragma("unroll") for (int _m = 0; _m < 4; ++_m) {                                 \
        a[_m][0] = *(const bf16x8*)(sc + (D) * 32768 + aBase + ((MH) * 4 + _m) * 2048 + ks0); \
        a[_m][1] = *(const bf16x8*)(sc + (D) * 32768 + aBase + ((MH) * 4 + _m) * 2048 + ks1); \
    }                                                                                  \
} while (0)
#define RD_B(D, NB) do {                                                               \
    _Pragma("unroll") for (int _n = 0; _n < 2; ++_n) {                                 \
        b[(NB) * 2 + _n][0] = *(const bf16x8*)(sc + (D) * 32768 + bBase + ((NB) * 2 + _n) * 2048 + ks0); \
        b[(NB) * 2 + _n][1] = *(const bf16x8*)(sc + (D) * 32768 + bBase + ((NB) * 2 + _n) * 2048 + ks1); \
    }                                                                                  \
} while (0)
#define MFMA16(MH, NB) do {                                                            \
    __builtin_amdgcn_s_setprio(1);                                                     \
    _Pragma("unroll") for (int _m = 0; _m < 4; ++_m)                                   \
    _Pragma("unroll") for (int _n = 0; _n < 2; ++_n)                                   \
    _Pragma("unroll") for (int _k = 0; _k < 2; ++_k)                                   \
        acc[(MH) * 4 + _m][(NB) * 2 + _n] = __builtin_amdgcn_mfma_f32_16x16x32_bf16(   \
            a[_m][_k], b[(NB) * 2 + _n][_k], acc[(MH) * 4 + _m][(NB) * 2 + _n], 0, 0, 0); \
    __builtin_amdgcn_s_setprio(0);                                                     \
} while (0)

template <int KDIM>
__global__ __launch_bounds__(512, 2) void gemm256(const bf16* __restrict__ A,
                                                  const bf16* __restrict__ Bt,
                                                  bf16* __restrict__ C,
                                                  const float* __restrict__ bias,
                                                  int N) {
    __shared__ bf16 smem[65536];  // 128 KiB: A[0:64K), B[64K:128K)
    char* sc = (char*)smem;

    const int tid  = threadIdx.x;
    const int wv   = tid >> 6;
    const int lane = tid & 63;
    const int ll   = lane & 15;
    const int kh   = lane >> 4;
    const int wm   = wv >> 2;  // 0..1
    const int wn   = wv & 3;   // 0..3
    const int m0   = blockIdx.x * 256;
    const int n0   = blockIdx.y * 256;

    // Staging: per-thread inverse-swizzled global source. Linear LDS dest byte
    // x0 = issue*8192 + tid*16; source element = (x0>>7 row, SWZ(x0)&127 colbyte)
    // with SWZ(x) = x ^ (((x>>7)&7)<<4)  => row unchanged, col-block permuted.
    const int swcol = (((tid & 7) ^ ((tid >> 3) & 7)) << 3);  // element offset
    const bf16* aSrc = A + (size_t)(m0 + (tid >> 3)) * KDIM + swcol;
    const bf16* bSrc = Bt + (size_t)(n0 + (tid >> 3)) * KDIM + swcol;
    char* aDst = sc + wv * 1024;
    char* bDst = sc + 65536 + wv * 1024;

    // Read side: lin = half*16384 + lr*128 + colbyte, swizzle XOR = ((lr&7)<<4)
    // with lr&7 == ll&7 for all fragments (mf*16 / nf*16 are multiples of 8).
    const int aBase = wm * 16384 + ll * 128;
    const int bBase = 65536 + (wn >> 1) * 16384 + ((wn & 1) * 64 + ll) * 128;
    const int ks0 = ((kh ^ (ll & 7)) << 4);        // k-slice 0 col-block byte
    const int ks1 = (((4 | kh) ^ (ll & 7)) << 4);  // k-slice 1

    f32x4 acc[8][4] = {};
    bf16x8 a[4][2], b[4][2];

    // ---- prologue: tile0 (buf0) fully + tile1.Ah0; wait tile0 ----
    STAGE_A(0, 0, 0); STAGE_A(0, 1, 0); STAGE_B(0, 0, 0); STAGE_B(0, 1, 0);
    STAGE_A(1, 0, 1);
    VMC(2); BAR();

    constexpr int NT = KDIM / 64;  // K-tiles (even, >=4)

    // ---- main loop: tiles t (buf0), t+1 (buf1); stage t+1 tail, t+2, t+3.h0
#pragma unroll 1
    for (int t = 0; t < NT - 2; t += 2) {
        RD_A(0, 0); RD_B(0, 0); STAGE_A(t + 1, 1, 1); BAR(); MFMA16(0, 0); BAR();
        RD_B(0, 1);             STAGE_B(t + 1, 0, 1); BAR(); MFMA16(0, 1); BAR();
        RD_A(0, 1);             STAGE_B(t + 1, 1, 1); BAR(); MFMA16(1, 1); BAR();
                                STAGE_A(t + 2, 0, 0); BAR(); MFMA16(1, 0); VMC(2); BAR();
        RD_A(1, 0); RD_B(1, 0); STAGE_A(t + 2, 1, 0); BAR(); MFMA16(0, 0); BAR();
        RD_B(1, 1);             STAGE_B(t + 2, 0, 0); BAR(); MFMA16(0, 1); BAR();
        RD_A(1, 1);             STAGE_B(t + 2, 1, 0); BAR(); MFMA16(1, 1); BAR();
                                STAGE_A(t + 3, 0, 1); BAR(); MFMA16(1, 0); VMC(2); BAR();
    }

    // ---- epilogue: tiles NT-2 (buf0), NT-1 (buf1); finish NT-1 staging ----
    {
        const int t = NT - 2;
        RD_A(0, 0); RD_B(0, 0); STAGE_A(t + 1, 1, 1); BAR(); MFMA16(0, 0); BAR();
        RD_B(0, 1);             STAGE_B(t + 1, 0, 1); BAR(); MFMA16(0, 1); BAR();
        RD_A(0, 1);             STAGE_B(t + 1, 1, 1); BAR(); MFMA16(1, 1); BAR();
                                                      BAR(); MFMA16(1, 0); VMC(0); BAR();
        RD_A(1, 0); RD_B(1, 0);                       BAR(); MFMA16(0, 0); BAR();
        RD_B(1, 1);                                   BAR(); MFMA16(0, 1); BAR();
        RD_A(1, 1);                                   BAR(); MFMA16(1, 1); BAR();
                                                             MFMA16(1, 0);
    }

    // ---- C write: row = wm*128+mf*16+kh*4+r, col = wn*64+nf*16+ll ----
#pragma unroll
    for (int nf = 0; nf < 4; ++nf) {
        const int col = n0 + wn * 64 + nf * 16 + ll;
        const float bv_ = bias[col];
#pragma unroll
        for (int mf = 0; mf < 8; ++mf) {
            const int row = m0 + wm * 128 + mf * 16 + kh * 4;
#pragma unroll
            for (int r = 0; r < 4; ++r)
                C[(size_t)(row + r) * N + col] = (bf16)(acc[mf][nf][r] + bv_);
        }
    }
}

// ---------------------------------------------------------------------------
// GEMM: C[M][N] = A[M][K](bf16) * Bt[N][K](bf16)^T + bias[N]
// m97-style: 128x128 tile, BK=32, 4 waves (2x2 of 64x64), 16x16x32 MFMA
// (kept for the output projection: N=1024 -> 256 blocks at 128^2)
// ---------------------------------------------------------------------------
template <typename OutT>
__global__ __launch_bounds__(256) void gemm_bt(const bf16* __restrict__ A,
                                               const bf16* __restrict__ Bt,
                                               OutT* __restrict__ C,
                                               const float* __restrict__ bias,
                                               int M, int N, int K) {
    __shared__ bf16 As[128 * 32];
    __shared__ bf16 Bs[128 * 32];
    const int tid  = threadIdx.x;
    const int wave = tid >> 6;
    const int lane = tid & 63;
    const int m0 = blockIdx.x * 128;
    const int n0 = blockIdx.y * 128;
    const int wm = (wave >> 1) * 64;   // wave's 64x64 quadrant
    const int wn = (wave & 1) * 64;
    const int lrow = lane & 15;
    const int kh   = lane >> 4;        // 0..3
    const int srow = lane >> 2;        // staging: 16 rows per wave chunk
    const int scol = (lane & 3) * 16;  // byte offset within 64B k-row

    f32x4 acc[4][4] = {};

    for (int k0 = 0; k0 < K; k0 += 32) {
#pragma unroll
        for (int half = 0; half < 2; ++half) {
            int rbase = half * 64 + wave * 16;
            const char* ga = (const char*)(A + (size_t)(m0 + rbase + srow) * K + k0) + scol;
            gload_lds16(ga, (char*)As + rbase * 64);
            const char* gb = (const char*)(Bt + (size_t)(n0 + rbase + srow) * K + k0) + scol;
            gload_lds16(gb, (char*)Bs + rbase * 64);
        }
        __syncthreads();
        bf16x8 af[4], bfr[4];
#pragma unroll
        for (int mf = 0; mf < 4; ++mf)
            af[mf] = *(const bf16x8*)&As[(wm + mf * 16 + lrow) * 32 + kh * 8];
#pragma unroll
        for (int nf = 0; nf < 4; ++nf)
            bfr[nf] = *(const bf16x8*)&Bs[(wn + nf * 16 + lrow) * 32 + kh * 8];
#pragma unroll
        for (int mf = 0; mf < 4; ++mf)
#pragma unroll
            for (int nf = 0; nf < 4; ++nf)
                acc[mf][nf] = __builtin_amdgcn_mfma_f32_16x16x32_bf16(af[mf], bfr[nf], acc[mf][nf], 0, 0, 0);
        __syncthreads();
    }

#pragma unroll
    for (int mf = 0; mf < 4; ++mf) {
#pragma unroll
        for (int nf = 0; nf < 4; ++nf) {
            int col = n0 + wn + nf * 16 + lrow;
            float bv_ = bias[col];
#pragma unroll
            for (int r = 0; r < 4; ++r) {
                int row = m0 + wm + mf * 16 + kh * 4 + r;
                C[(size_t)row * N + col] = (OutT)(acc[mf][nf][r] + bv_);
            }
        }
    }
}

// ---------------------------------------------------------------------------
// V column sums, stage 1: partial[b*64+chunk][1024] = sum of 32 rows of V
// ---------------------------------------------------------------------------
__global__ __launch_bounds__(256) void vsum_part(const bf16* __restrict__ qkv,
                                                 float* __restrict__ part) {
    int blk = blockIdx.x;       // 0..127
    int b = blk >> 6, chunk = blk & 63;
    int cg = threadIdx.x & 127; // column group of 8
    int jp = threadIdx.x >> 7;  // 0..1
    int j0 = chunk * 32 + jp * 16;

    float acc[8] = {};
#pragma unroll
    for (int r = 0; r < 16; ++r) {
        int j = j0 + r;
        bf16x8 v = *(const bf16x8*)&qkv[(size_t)(b * S_LEN + j) * 3072 + 2048 + cg * 8];
#pragma unroll
        for (int e = 0; e < 8; ++e) acc[e] += (float)v[e];
    }

    __shared__ float red[256][8];
#pragma unroll
    for (int e = 0; e < 8; ++e) red[threadIdx.x][e] = acc[e];
    __syncthreads();
    if (jp == 0) {
        float* outp = part + ((size_t)blk << 10) + cg * 8;
#pragma unroll
        for (int e = 0; e < 8; ++e)
            outp[e] = red[threadIdx.x][e] + red[threadIdx.x + 128][e];
    }
}

// ---------------------------------------------------------------------------
// V column sums, stage 2: vsum[b*1024 + col] = sum over 64 chunks
// ---------------------------------------------------------------------------
__global__ void vsum_final(const float* __restrict__ part, float* __restrict__ vsum) {
    int idx = blockIdx.x * 256 + threadIdx.x;  // 0..2047
    int b = idx >> 10, col = idx & 1023;
    float s = 0.f;
#pragma unroll
    for (int c = 0; c < 64; ++c) s += part[(((size_t)b * 64 + c) << 10) + col];
    vsum[idx] = s;  // layout [b][h][d] == b*1024 + h*64 + d
}

// ---------------------------------------------------------------------------
// Band attention. Per block: one (b, h, 64-row i-tile).
//   w_ij = expm1(q_i . k_j / 8)  for |i-j| <= 8, 0 <= j < S
//   ctx_i = (sum_j w_ij v_j + Vsum) / (sum_j w_ij + S)
// ---------------------------------------------------------------------------
__global__ __launch_bounds__(256) void band_attn(const bf16* __restrict__ qkv,
                                                 const float* __restrict__ vsum,
                                                 bf16* __restrict__ ctx) {
    int bid = blockIdx.x;
    int it = bid & 31;
    int h  = (bid >> 5) & 15;
    int b  = bid >> 9;
    const int i0 = it * 64;

    __shared__ bf16 qs[64 * 72];
    __shared__ bf16 ks[80 * 72];
    __shared__ bf16 vs[80 * 72];
    __shared__ float wsc[64 * 19];
    __shared__ float wsum[64];

    int tid = threadIdx.x;

    for (int idx = tid; idx < 64 * 8; idx += 256) {
        int r = idx >> 3, c = idx & 7;
        size_t g = (size_t)(b * S_LEN + i0 + r) * 3072 + h * 64 + c * 8;
        *(int4*)&qs[r * 72 + c * 8] = *(const int4*)&qkv[g];
    }
    for (int idx = tid; idx < 80 * 8; idx += 256) {
        int r = idx >> 3, c = idx & 7;
        int j = i0 - 8 + r;
        int4 kv = {0, 0, 0, 0}, vv = {0, 0, 0, 0};
        if (j >= 0 && j < S_LEN) {
            size_t base = (size_t)(b * S_LEN + j) * 3072 + h * 64 + c * 8;
            kv = *(const int4*)&qkv[base + 1024];
            vv = *(const int4*)&qkv[base + 2048];
        }
        *(int4*)&ks[r * 72 + c * 8] = kv;
        *(int4*)&vs[r * 72 + c * 8] = vv;
    }
    __syncthreads();

    {
        int i = tid >> 2, jg = tid & 3;
        for (int jj = jg; jj < 17; jj += 4) {
            int j = i0 + i - 8 + jj;
            float w = 0.f;
            if (j >= 0 && j < S_LEN) {
                float dot = 0.f;
#pragma unroll
                for (int c = 0; c < 8; ++c) {
                    bf16x8 qv = *(const bf16x8*)&qs[i * 72 + c * 8];
                    bf16x8 kv = *(const bf16x8*)&ks[(i + jj) * 72 + c * 8];
#pragma unroll
                    for (int e = 0; e < 8; ++e) dot += (float)qv[e] * (float)kv[e];
                }
                w = expm1f(dot * 0.125f);
            }
            wsc[i * 19 + jj] = w;
        }
    }
    __syncthreads();
    if (tid < 64) {
        float s = 0.f;
#pragma unroll
        for (int jj = 0; jj < 17; ++jj) s += wsc[tid * 19 + jj];
        wsum[tid] = s + (float)S_LEN;
    }
    __syncthreads();

    {
        int d = tid & 63, ig = tid >> 6;
        float vbase = vsum[(b * NH + h) * HD_DIM + d];
        for (int i = ig; i < 64; i += 4) {
            float acc = vbase;
#pragma unroll
            for (int jj = 0; jj < 17; ++jj)
                acc += wsc[i * 19 + jj] * (float)vs[(i + jj) * 72 + d];
            ctx[(size_t)(b * S_LEN + i0 + i) * 1024 + h * 64 + d] = (bf16)(acc / wsum[i]);
        }
    }
}

// ---------------------------------------------------------------------------
extern "C" void kernel_launch(void* const* d_in, const int* in_sizes, int n_in,
                              void* d_out, int out_size, void* d_ws, size_t ws_size,
                              hipStream_t stream) {
    const float* x  = (const float*)d_in[0];
    const float* Wq = (const float*)d_in[1];
    const float* Wk = (const float*)d_in[2];
    const float* Wv = (const float*)d_in[3];
    const float* Wo = (const float*)d_in[4];
    const float* bq = (const float*)d_in[5];
    const float* bk = (const float*)d_in[6];
    const float* bv = (const float*)d_in[7];
    const float* bo = (const float*)d_in[8];

    char* ws = (char*)d_ws;
    bf16*  xb    = (bf16*)(ws);                       // 8 MB   x as bf16
    bf16*  wtall = (bf16*)(ws + 8388608);             // 6 MB   [Wq^T;Wk^T;Wv^T] bf16 [3072][1024]
    bf16*  wot   = (bf16*)(ws + 14680064);            // 2 MB   Wo^T bf16 [1024][1024]
    float* ball  = (float*)(ws + 16777216);           // 12 KB  bias concat [3072]
    bf16*  qkv   = (bf16*)(ws + 16789504);            // 24 MB  [4096][3072] bf16
    bf16*  ctxb  = (bf16*)(ws + 41955328);            // 8 MB   ctx bf16 [4096][1024]
    float* vsm   = (float*)(ws + 50343936);           // 8 KB   [32][64] == [b][h][d]
    float* vpart = (float*)(ws);                      // aliases xb (dead after QKV GEMM)

    cvt_f32_bf16<<<4096, 256, 0, stream>>>(x, xb, 4194304);
    dim3 tg(16, 16);
    transpose_cvt<<<tg, 256, 0, stream>>>(Wq, wtall);
    transpose_cvt<<<tg, 256, 0, stream>>>(Wk, wtall + 1024 * 1024);
    transpose_cvt<<<tg, 256, 0, stream>>>(Wv, wtall + 2 * 1024 * 1024);
    transpose_cvt<<<tg, 256, 0, stream>>>(Wo, wot);
    bias_concat<<<12, 256, 0, stream>>>(bq, bk, bv, ball);

    // QKV projection: [4096][1024] x [3072][1024]^T -> [4096][3072] bf16
    gemm256<1024><<<dim3(16, 12), 512, 0, stream>>>(xb, wtall, qkv, ball, 3072);

    vsum_part<<<128, 256, 0, stream>>>(qkv, vpart);
    vsum_final<<<8, 256, 0, stream>>>(vpart, vsm);
    band_attn<<<1024, 256, 0, stream>>>(qkv, vsm, ctxb);

    // output projection -> d_out fp32
    gemm_bt<float><<<dim3(32, 8), 256, 0, stream>>>(ctxb, wot, (float*)d_out, bo, 4096, 1024, 1024);
}